// Round 9
// baseline (196.719 us; speedup 1.0000x reference)
//
#include <hip/hip_runtime.h>
#include <math.h>

// TSMixerH: B=32,C=256,L=336,O=96,K=4,NL=2,DFF=1024
// Round 9 = Round 8 with ext_vector_type for non-temporal builtins
// (HIP float4/uint4 are classes -> rejected by __builtin_nontemporal_*).
//  - prep: NT loads of W (read-once), NT stores of wbuf (avoid
//    write-allocate of freshly-poisoned ws lines; don't dirty L2)
//  - mlp: NT loads of x, NT stores of out (out lines falsely shared
//    across XCDs due to cluster grouping -> write-allocate RMW thrash)

typedef unsigned short u16;
typedef unsigned int u32;
typedef unsigned long long u64;

constexpr int B = 32, C = 256, L = 336, O = 96, K = 4, NL = 2, DFF = 1024;
constexpr int TM = 32;
constexpr int NTILES = (B * C) / TM;  // 256
constexpr int LP = 352;               // L padded to mult of 32
constexpr int KS1 = LP / 32;          // 11
constexpr int KS2 = DFF / 32;         // 32
constexpr int NT2 = LP / 16;          // 22
constexpr int NTH = O / 16;           // 6
constexpr int ZBS = 360;              // bf16 z row stride (u16)
constexpr int HS = 1032;              // bf16 H row stride (u16)

constexpr int W1FRAGS = (DFF / 16) * KS1 * 64;  // 45056
constexpr int W2FRAGS = NT2 * KS2 * 64;         // 45056
constexpr int WHFRAGS = NTH * KS1 * 64;         // 4224
constexpr int NW1 = W1FRAGS * K * NL;           // 360448
constexpr int NW2 = W2FRAGS * K * NL;           // 360448
constexpr int NPREP = 176 + 256 + 44 + 1;       // 477 blocks

typedef __bf16 bf16x8 __attribute__((ext_vector_type(8)));
typedef float f32x4 __attribute__((ext_vector_type(4)));
typedef float fx4 __attribute__((ext_vector_type(4)));  // NT-capable
typedef u32 ux4 __attribute__((ext_vector_type(4)));    // NT-capable

__device__ __forceinline__ u16 f2bf(float f) {
  union { float f; u32 u; } v;
  v.f = f;
  u32 r = v.u + 0x7fffu + ((v.u >> 16) & 1u);  // RNE
  return (u16)(r >> 16);
}
__device__ __forceinline__ float bf2f(u16 h) {
  union { u32 u; float f; } v;
  v.u = ((u32)h) << 16;
  return v.f;
}
__device__ __forceinline__ u32 pack2(float a, float b) {
  return (u32)f2bf(a) | ((u32)f2bf(b) << 16);
}

// ---- merged prep: repacks (blocks 0..475) + tables (block 476) ----
// Fragment semantics (verified passing r3-r7):
//   A-frag (16x16x32): lane holds A[m=lane&15][k=(lane>>4)*8+j], j=0..7.
//   w1 frag(kl,nt,ks)[lane][j] = W1[kl][l=ks*32+q*8+j][d=nt*16+rm] (0 if l>=L)
//   w2 frag(kl,nt,ks)[lane][j] = W2[kl][d=ks*32+q*8+j][l=nt*16+rm] (0 if l>=L)
//   wh frag(kk,nt,ks)[lane][j] = Wh[kk][l=ks*32+q*8+j][o=nt*16+rm] (0 if l>=L)
// meta (ints): [0..255] tiles (k<<16|rstart), [256..511] chlist, [512..] cofs
__global__ __launch_bounds__(256) void prep(const int* __restrict__ assign,
                                            const float* __restrict__ W1,
                                            const float* __restrict__ W2,
                                            const float* __restrict__ Wh,
                                            int* __restrict__ meta,
                                            u16* __restrict__ wbuf) {
  __shared__ u16 sm[32][516];
  const int bid = blockIdx.x;
  const int tid = threadIdx.x;
  const int wid = tid >> 6, lane = tid & 63;
  const int q = lane >> 4, rm = lane & 15;

  if (bid < 176) {  // ---- W1 ----
    const int dh = bid & 1;
    const int ks = (bid >> 1) % 11;
    const int kl = bid / 22;
    for (int rr = 0; rr < 8; ++rr) {
      const int r = wid * 8 + rr;
      const int l = ks * 32 + r;
#pragma unroll
      for (int h = 0; h < 2; ++h) {
        const int c = h * 256 + lane * 4;
        fx4 v = {0.f, 0.f, 0.f, 0.f};
        if (l < L)
          v = __builtin_nontemporal_load(
              (const fx4*)(W1 + ((size_t)kl * L + l) * DFF + dh * 512 + c));
        uint2 p;
        p.x = pack2(v[0], v[1]);
        p.y = pack2(v[2], v[3]);
        *(uint2*)&sm[r][c] = p;
      }
    }
    __syncthreads();
    for (int e = 0; e < 8; ++e) {
      const int ntl = wid * 8 + e;
      const int nt = dh * 32 + ntl;
      ux4 o;
#pragma unroll
      for (int jj = 0; jj < 4; ++jj) {
        const u16 a = sm[q * 8 + 2 * jj][ntl * 16 + rm];
        const u16 b = sm[q * 8 + 2 * jj + 1][ntl * 16 + rm];
        o[jj] = (u32)a | ((u32)b << 16);
      }
      __builtin_nontemporal_store(
          o, (ux4*)(wbuf + ((size_t)(kl * 64 + nt) * 11 + ks) * 512 +
                    lane * 8));
    }
  } else if (bid < 432) {  // ---- W2 ----
    const int b2i = bid - 176;
    const int ks = b2i & 31;
    const int kl = b2i >> 5;
    for (int rr = 0; rr < 8; ++rr) {
      const int r = wid * 8 + rr;  // local d
      const float* row = W2 + ((size_t)kl * DFF + ks * 32 + r) * L;
      {
        const int c = lane * 4;  // 0..255
        const fx4 v = __builtin_nontemporal_load((const fx4*)(row + c));
        uint2 p;
        p.x = pack2(v[0], v[1]);
        p.y = pack2(v[2], v[3]);
        *(uint2*)&sm[r][c] = p;
      }
      {
        const int c = 256 + lane * 4;  // 256..511; keep c<352, zero c>=336
        if (c < 352) {
          fx4 v = {0.f, 0.f, 0.f, 0.f};
          if (c < L) v = __builtin_nontemporal_load((const fx4*)(row + c));
          uint2 p;
          p.x = pack2(v[0], v[1]);
          p.y = pack2(v[2], v[3]);
          *(uint2*)&sm[r][c] = p;
        }
      }
    }
    __syncthreads();
    for (int nt = wid; nt < NT2; nt += 4) {
      ux4 o;
#pragma unroll
      for (int jj = 0; jj < 4; ++jj) {
        const u16 a = sm[q * 8 + 2 * jj][nt * 16 + rm];
        const u16 b = sm[q * 8 + 2 * jj + 1][nt * 16 + rm];
        o[jj] = (u32)a | ((u32)b << 16);
      }
      __builtin_nontemporal_store(
          o, (ux4*)(wbuf + (size_t)NW1 * 8 +
                    ((size_t)(kl * 22 + nt) * 32 + ks) * 512 + lane * 8));
    }
  } else if (bid < 476) {  // ---- Wh ----
    const int b3i = bid - 432;
    const int ks = b3i % 11;
    const int kk = b3i / 11;
    for (int rr = 0; rr < 8; ++rr) {
      const int r = wid * 8 + rr;
      const int l = ks * 32 + r;
      if (lane < 24) {
        const int c = lane * 4;
        fx4 v = {0.f, 0.f, 0.f, 0.f};
        if (l < L)
          v = __builtin_nontemporal_load(
              (const fx4*)(Wh + ((size_t)kk * L + l) * O + c));
        uint2 p;
        p.x = pack2(v[0], v[1]);
        p.y = pack2(v[2], v[3]);
        *(uint2*)&sm[r][c] = p;
      }
    }
    __syncthreads();
    for (int nt = wid; nt < NTH; nt += 4) {
      ux4 o;
#pragma unroll
      for (int jj = 0; jj < 4; ++jj) {
        const u16 a = sm[q * 8 + 2 * jj][nt * 16 + rm];
        const u16 b = sm[q * 8 + 2 * jj + 1][nt * 16 + rm];
        o[jj] = (u32)a | ((u32)b << 16);
      }
      __builtin_nontemporal_store(
          o, (ux4*)(wbuf + (size_t)(NW1 + NW2) * 8 +
                    ((size_t)(kk * 6 + nt) * 11 + ks) * 512 + lane * 8));
    }
  } else {  // ---- tables ----
    __shared__ int wcnt[4][K];
    __shared__ int pre[4][K];
    __shared__ int cofs[K + 1];
    const int a = assign[tid];
    const u64 below = (1ull << lane) - 1ull;
    int myrank = 0;
#pragma unroll
    for (int k = 0; k < K; ++k) {
      const u64 m = __ballot(a == k);
      if (a == k) myrank = (int)__popcll(m & below);
      if (lane == 0) wcnt[wid][k] = (int)__popcll(m);
    }
    __syncthreads();
    if (tid == 0) {
      int tot[K];
      for (int k = 0; k < K; ++k) {
        int s = 0;
        for (int ww = 0; ww < 4; ++ww) {
          pre[ww][k] = s;
          s += wcnt[ww][k];
        }
        tot[k] = s;
      }
      cofs[0] = 0;
      for (int k = 0; k < K; ++k) cofs[k + 1] = cofs[k] + tot[k];
      for (int k = 0; k <= K; ++k) meta[512 + k] = cofs[k];
    }
    __syncthreads();
    const int pos = cofs[a] + pre[wid][a] + myrank;
    meta[256 + pos] = tid;  // chlist
    int k = 0;
    while (k < K - 1 && tid >= cofs[k + 1]) ++k;
    meta[tid] = (k << 16) | ((tid - cofs[k]) * TM);
  }
}

// ---- main kernel: 16 waves/block, 1 block/CU ----
__global__ __launch_bounds__(1024, 4) void mlp_mfma(
    const float* __restrict__ x, const float* __restrict__ rev_w,
    const float* __restrict__ rev_b, const float* __restrict__ b1,
    const float* __restrict__ b2, const float* __restrict__ bh,
    const int* __restrict__ meta, const u16* __restrict__ wbuf,
    float* __restrict__ out) {
  __shared__ __align__(16) u16 zb[TM][ZBS];  // 23.0 KB
  __shared__ __align__(16) u16 Hsh[TM][HS];  // 66.0 KB
  __shared__ float s_mean[TM], s_std[TM], s_rw[TM], s_rb[TM];
  __shared__ int s_b[TM], s_c[TM];

  const int tid = threadIdx.x;
  const int wid = tid >> 6;  // 0..15
  const int lane = tid & 63;
  const int q = lane >> 4, rm = lane & 15;

  // cluster->XCD affinity: tiles cluster-sorted; XCD (bid&7) gets a
  // contiguous 32-tile range -> per-XCD weight working set ~1 cluster.
  const int swz = (blockIdx.x & 7) * 32 + (blockIdx.x >> 3);
  const int info = meta[swz];
  const int kcl = info >> 16;
  const int rstart = info & 0xffff;
  const int cofs = meta[512 + kcl];
  const int cnt = meta[512 + kcl + 1] - cofs;

  // ---- RevIN: 2 rows per wave (NT x loads: read-once stream) ----
  for (int i = 0; i < 2; ++i) {
    const int t = wid * 2 + i;
    const int ri = rstart + t;
    const int b = ri / cnt;
    const int c = meta[256 + cofs + (ri % cnt)];
    const float* xrow = x + (size_t)(b * C + c) * L;
    float v[6], s = 0.f, s2 = 0.f;
#pragma unroll
    for (int jj = 0; jj < 6; ++jj) {
      const int j = lane + jj * 64;
      v[jj] = (j < L) ? __builtin_nontemporal_load(xrow + j) : 0.f;
      s += v[jj];
      s2 += v[jj] * v[jj];
    }
#pragma unroll
    for (int off = 32; off > 0; off >>= 1) {
      s += __shfl_down(s, off);
      s2 += __shfl_down(s2, off);
    }
    s = __shfl(s, 0);
    s2 = __shfl(s2, 0);
    const float mean = s * (1.f / L);
    const float var = s2 * (1.f / L) - mean * mean;
    const float stdv = sqrtf(var + 1e-5f);
    const float rstd = 1.f / stdv;
    const float rw = rev_w[c], rb_ = rev_b[c];
#pragma unroll
    for (int jj = 0; jj < 6; ++jj) {
      const int j = lane + jj * 64;
      if (j < L) zb[t][j] = f2bf((v[jj] - mean) * rstd * rw + rb_);
    }
    if (lane < LP - L) zb[t][L + lane] = 0;
    if (lane == 0) {
      s_mean[t] = mean;
      s_std[t] = stdv;
      s_rw[t] = rw;
      s_rb[t] = rb_;
      s_b[t] = b;
      s_c[t] = c;
    }
  }

  const u16* w1b = wbuf;
  const u16* w2b = wbuf + (size_t)NW1 * 8;
  const u16* whb = wbuf + (size_t)(NW1 + NW2) * 8;
  constexpr int TS1 = KS1 * 512;  // 5632  (u16 per d-tile, W1)
  constexpr int TS2 = KS2 * 512;  // 16384 (u16 per l-tile, W2)

  // preload layer-0 W1 ring (4 d-tiles/wave) before the barrier (global-only)
  bf16x8 acur[4], anxt[4];
  {
    const u16* base = w1b + (size_t)(kcl * NL) * W1FRAGS * 8 +
                      (size_t)(wid * 4) * TS1 + lane * 8;
#pragma unroll
    for (int t = 0; t < 4; ++t) {
      acur[t] = *(const bf16x8*)(base + (size_t)t * TS1);
      anxt[t] = *(const bf16x8*)(base + (size_t)t * TS1 + 512);
    }
  }
  __syncthreads();  // zb ready

  // ---- fp32 residual masters (D-layout): l-tiles wid, wid+16 (wid<6) ----
  f32x4 zm[2][2];
#pragma unroll
  for (int tt = 0; tt < 2; ++tt) {
    const int nt2 = wid + 16 * tt;
#pragma unroll
    for (int rg = 0; rg < 2; ++rg) {
      if (nt2 < NT2) {
        const uint2 zw = *(const uint2*)&zb[rm + 16 * rg][nt2 * 16 + q * 4];
        zm[tt][rg] = f32x4{bf2f((u16)zw.x), bf2f((u16)(zw.x >> 16)),
                           bf2f((u16)zw.y), bf2f((u16)(zw.y >> 16))};
      } else {
        zm[tt][rg] = f32x4{0.f, 0.f, 0.f, 0.f};
      }
    }
  }

  for (int l = 0; l < NL; ++l) {
    const int kl = kcl * NL + l;
    const u16* W1f = w1b + (size_t)kl * W1FRAGS * 8;
    const u16* W2f = w2b + (size_t)kl * W2FRAGS * 8;
    const float* b1p = b1 + kl * DFF;
    const float* b2p = b2 + kl * L;
    const u16* base1 = W1f + (size_t)(wid * 4) * TS1 + lane * 8;

    // -- phase 1: H = relu(z @ W1 + b1); wave owns 4 d-tiles, depth-2 ring
    f32x4 acc[4][2];
#pragma unroll
    for (int t = 0; t < 4; ++t)
#pragma unroll
      for (int rg = 0; rg < 2; ++rg) acc[t][rg] = f32x4{0.f, 0.f, 0.f, 0.f};
#pragma unroll 2
    for (int ks = 0; ks < KS1; ++ks) {
      bf16x8 ause[4];
#pragma unroll
      for (int t = 0; t < 4; ++t) {
        ause[t] = acur[t];
        acur[t] = anxt[t];
      }
      if (ks + 2 < KS1) {
#pragma unroll
        for (int t = 0; t < 4; ++t)
          anxt[t] = *(const bf16x8*)(base1 + (size_t)t * TS1 + (ks + 2) * 512);
      }
      const bf16x8 zf0 = *(const bf16x8*)&zb[rm][ks * 32 + q * 8];
      const bf16x8 zf1 = *(const bf16x8*)&zb[rm + 16][ks * 32 + q * 8];
#pragma unroll
      for (int t = 0; t < 4; ++t) {
        acc[t][0] = __builtin_amdgcn_mfma_f32_16x16x32_bf16(ause[t], zf0,
                                                            acc[t][0], 0, 0, 0);
        acc[t][1] = __builtin_amdgcn_mfma_f32_16x16x32_bf16(ause[t], zf1,
                                                            acc[t][1], 0, 0, 0);
      }
    }
#pragma unroll
    for (int t = 0; t < 4; ++t) {
      const int nt = wid * 4 + t;
      const float4 bq = *(const float4*)(b1p + nt * 16 + q * 4);
#pragma unroll
      for (int rg = 0; rg < 2; ++rg) {
        uint2 hw;
        hw.x = pack2(fmaxf(acc[t][rg][0] + bq.x, 0.f),
                     fmaxf(acc[t][rg][1] + bq.y, 0.f));
        hw.y = pack2(fmaxf(acc[t][rg][2] + bq.z, 0.f),
                     fmaxf(acc[t][rg][3] + bq.w, 0.f));
        *(uint2*)&Hsh[rm + 16 * rg][nt * 16 + q * 4] = hw;
      }
    }

    // preload phase-2 ring (ks=0,1,2) before the barrier (global-only)
    const u16* base2 = W2f + lane * 8;
    bf16x8 wq0[2], wq1[2], wq2[2];
#pragma unroll
    for (int tt = 0; tt < 2; ++tt) {
      const int nt2 = wid + 16 * tt;
      if (nt2 < NT2) {
        wq0[tt] = *(const bf16x8*)(base2 + (size_t)nt2 * TS2);
        wq1[tt] = *(const bf16x8*)(base2 + (size_t)nt2 * TS2 + 512);
        wq2[tt] = *(const bf16x8*)(base2 + (size_t)nt2 * TS2 + 1024);
      }
    }
    __syncthreads();  // Hsh ready

    // -- phase 2: zm += H @ W2; depth-3 ring, <=2 tile streams
#pragma unroll 2
    for (int ks = 0; ks < KS2; ++ks) {
      bf16x8 wuse[2];
#pragma unroll
      for (int tt = 0; tt < 2; ++tt) {
        wuse[tt] = wq0[tt];
        wq0[tt] = wq1[tt];
        wq1[tt] = wq2[tt];
      }
      if (ks + 3 < KS2) {
#pragma unroll
        for (int tt = 0; tt < 2; ++tt) {
          const int nt2 = wid + 16 * tt;
          if (nt2 < NT2)
            wq2[tt] =
                *(const bf16x8*)(base2 + (size_t)nt2 * TS2 + (ks + 3) * 512);
        }
      }
      const bf16x8 hf0 = *(const bf16x8*)&Hsh[rm][ks * 32 + q * 8];
      const bf16x8 hf1 = *(const bf16x8*)&Hsh[rm + 16][ks * 32 + q * 8];
#pragma unroll
      for (int tt = 0; tt < 2; ++tt) {
        if (wid + 16 * tt < NT2) {
          zm[tt][0] = __builtin_amdgcn_mfma_f32_16x16x32_bf16(wuse[tt], hf0,
                                                              zm[tt][0], 0, 0, 0);
          zm[tt][1] = __builtin_amdgcn_mfma_f32_16x16x32_bf16(wuse[tt], hf1,
                                                              zm[tt][1], 0, 0, 0);
        }
      }
    }

    // -- epilogue: zm += b2, refresh bf16 zb
#pragma unroll
    for (int tt = 0; tt < 2; ++tt) {
      const int nt2 = wid + 16 * tt;
      if (nt2 < NT2) {
        const int lc = nt2 * 16 + q * 4;
        if (lc < L) {
          const float4 bq = *(const float4*)(b2p + lc);
          zm[tt][0][0] += bq.x; zm[tt][0][1] += bq.y;
          zm[tt][0][2] += bq.z; zm[tt][0][3] += bq.w;
          zm[tt][1][0] += bq.x; zm[tt][1][1] += bq.y;
          zm[tt][1][2] += bq.z; zm[tt][1][3] += bq.w;
        }
#pragma unroll
        for (int rg = 0; rg < 2; ++rg) {
          uint2 zw;
          zw.x = pack2(zm[tt][rg][0], zm[tt][rg][1]);
          zw.y = pack2(zm[tt][rg][2], zm[tt][rg][3]);
          *(uint2*)&zb[rm + 16 * rg][lc] = zw;
        }
      }
    }

    // preload next layer's W1 ring before the barrier (global-only)
    if (l + 1 < NL) {
      const u16* nb = w1b + (size_t)(kl + 1) * W1FRAGS * 8 +
                      (size_t)(wid * 4) * TS1 + lane * 8;
#pragma unroll
      for (int t = 0; t < 4; ++t) {
        acur[t] = *(const bf16x8*)(nb + (size_t)t * TS1);
        anxt[t] = *(const bf16x8*)(nb + (size_t)t * TS1 + 512);
      }
    }
    __syncthreads();  // zb final for this layer; Hsh free for next
  }

  // ---- head: y = z @ Wh + bh, denorm, NT scatter out[b][o][c] ----
  if (wid < NTH) {
    const u16* Whf =
        whb + (size_t)kcl * WHFRAGS * 8 + (size_t)wid * TS1 + lane * 8;
    f32x4 acc0 = {0.f, 0.f, 0.f, 0.f}, acc1 = {0.f, 0.f, 0.f, 0.f};
    for (int ks = 0; ks < KS1; ++ks) {
      const bf16x8 af = *(const bf16x8*)(Whf + ks * 512);
      const bf16x8 zf0 = *(const bf16x8*)&zb[rm][ks * 32 + q * 8];
      const bf16x8 zf1 = *(const bf16x8*)&zb[rm + 16][ks * 32 + q * 8];
      acc0 = __builtin_amdgcn_mfma_f32_16x16x32_bf16(af, zf0, acc0, 0, 0, 0);
      acc1 = __builtin_amdgcn_mfma_f32_16x16x32_bf16(af, zf1, acc1, 0, 0, 0);
    }
    const float4 bq = *(const float4*)(bh + kcl * O + wid * 16 + q * 4);
    const float bqa[4] = {bq.x, bq.y, bq.z, bq.w};
#pragma unroll
    for (int rg = 0; rg < 2; ++rg) {
      const int row = rm + 16 * rg;
      const float mean = s_mean[row], stdv = s_std[row];
      const float rw = s_rw[row], rb_ = s_rb[row];
      const int ob = s_b[row], oc = s_c[row];
      const f32x4 acc = rg ? acc1 : acc0;
#pragma unroll
      for (int gg = 0; gg < 4; ++gg) {
        const int o = wid * 16 + q * 4 + gg;
        const float y = acc[gg] + bqa[gg];
        __builtin_nontemporal_store((y - rb_) / rw * stdv + mean,
                                    &out[((size_t)ob * O + o) * C + oc]);
      }
    }
  }
}

extern "C" void kernel_launch(void* const* d_in, const int* in_sizes, int n_in,
                              void* d_out, int out_size, void* d_ws,
                              size_t ws_size, hipStream_t stream) {
  const float* x = (const float*)d_in[0];
  const float* rev_w = (const float*)d_in[1];
  const float* rev_b = (const float*)d_in[2];
  const float* W1 = (const float*)d_in[3];
  const float* b1 = (const float*)d_in[4];
  const float* W2 = (const float*)d_in[5];
  const float* b2 = (const float*)d_in[6];
  const float* Wh = (const float*)d_in[7];
  const float* bh = (const float*)d_in[8];
  const int* assign = (const int*)d_in[9];
  float* out = (float*)d_out;

  int* meta = (int*)d_ws;                  // ~2.1 KB
  u16* wbuf = (u16*)((char*)d_ws + 4096);  // 11.8 MB bf16 fragments

  prep<<<NPREP, 256, 0, stream>>>(assign, W1, W2, Wh, meta, wbuf);
  mlp_mfma<<<NTILES, 1024, 0, stream>>>(x, rev_w, rev_b, b1, b2, bh, meta,
                                        wbuf, out);
}

// Round 10
// 143.229 us; speedup vs baseline: 1.3735x; 1.3735x over previous
//
#include <hip/hip_runtime.h>
#include <math.h>

// TSMixerH: B=32,C=256,L=336,O=96,K=4,NL=2,DFF=1024
// Round 10:
//  - REVERT all non-temporal access (r9: +28us regression, WRITE_SIZE
//    unchanged -> write-allocate theory falsified; NT wbuf stores starve
//    mlp's weight reads of L2)
//  - mlp phases 1/2 converted to mfma_f32_32x32x16_bf16: 2x FLOP per
//    loaded A-byte (16384 MACs / 16B-lane vs 8192), 8-cyc issue vs 4.8
//    -> halves weight-load pressure, doubles latency tolerance. TM=32
//    fits N=32 exactly (one N-tile). Head stays 16x16 (verified path).
//  - depth-4 (phase1) / depth-8 (phase2) modulo register rings, full
//    unroll -> static slot indices, no shift moves, more MLP for the
//    cold-L2 replays the timed bench sees (poison fill flushes L2).

typedef unsigned short u16;
typedef unsigned int u32;
typedef unsigned long long u64;

constexpr int B = 32, C = 256, L = 336, O = 96, K = 4, NL = 2, DFF = 1024;
constexpr int TM = 32;
constexpr int NTILES = (B * C) / TM;  // 256
constexpr int LP = 352;               // L padded
constexpr int ZBS = 360;              // bf16 z row stride (u16)
constexpr int HS = 1032;              // bf16 H row stride (u16)

constexpr int DT1 = 32;  // phase-1 d-tiles (32-wide)
constexpr int KT1 = 22;  // phase-1 k-steps (16-deep over LP)
constexpr int LT2 = 11;  // phase-2 l-tiles (32-wide)
constexpr int KT2 = 64;  // phase-2 k-steps (16-deep over DFF)
constexpr int NTH = 6;   // head o-tiles (16x16 path)
constexpr int KSH = 11;  // head k-steps (32-deep)

constexpr int TS1 = KT1 * 512;  // 11264 u16 per d-tile
constexpr int TS2 = KT2 * 512;  // 32768 u16 per l-tile
constexpr int THS = KSH * 512;  // 5632 u16 per o-tile

constexpr int W1FRAGS = DT1 * KT1 * 64;  // 45056
constexpr int W2FRAGS = LT2 * KT2 * 64;  // 45056
constexpr int WHFRAGS = NTH * KSH * 64;  // 4224
constexpr int NW1 = W1FRAGS * K * NL;    // 360448
constexpr int NW2 = W2FRAGS * K * NL;    // 360448
constexpr int NPREP = 176 + 256 + 44 + 1;

typedef __bf16 bf16x8 __attribute__((ext_vector_type(8)));
typedef float f32x4 __attribute__((ext_vector_type(4)));
typedef float f32x16 __attribute__((ext_vector_type(16)));

__device__ __forceinline__ u16 f2bf(float f) {
  union { float f; u32 u; } v;
  v.f = f;
  u32 r = v.u + 0x7fffu + ((v.u >> 16) & 1u);  // RNE
  return (u16)(r >> 16);
}
__device__ __forceinline__ float bf2f(u16 h) {
  union { u32 u; float f; } v;
  v.u = ((u32)h) << 16;
  return v.f;
}
__device__ __forceinline__ u32 pack2(float a, float b) {
  return (u32)f2bf(a) | ((u32)f2bf(b) << 16);
}

// ---- merged prep: repacks (blocks 0..475) + tables (block 476) ----
// 32x32x16 A-frag: lane holds A[m=lane&31][k=(lane>>5)*8+j], j=0..7.
//  w1 frag(kl,dt,ks)[lane][j] = W1[kl][l=16ks+(lane>>5)*8+j][d=32dt+(lane&31)]
//  w2 frag(kl,lt,ks)[lane][j] = W2[kl][d=16ks+(lane>>5)*8+j][l=32lt+(lane&31)]
// 16x16x32 A-frag (head, unchanged): lane holds A[m=lane&15][k=(lane>>4)*8+j]
//  wh frag(kk,nt,ks)[lane][j] = Wh[kk][l=32ks+(lane>>4)*8+j][o=16nt+(lane&15)]
// all zero-padded where l>=L.
// meta (ints): [0..255] tiles (k<<16|rstart), [256..511] chlist, [512..] cofs
__global__ __launch_bounds__(256) void prep(const int* __restrict__ assign,
                                            const float* __restrict__ W1,
                                            const float* __restrict__ W2,
                                            const float* __restrict__ Wh,
                                            int* __restrict__ meta,
                                            u16* __restrict__ wbuf) {
  __shared__ u16 sm[32][516];
  const int bid = blockIdx.x;
  const int tid = threadIdx.x;
  const int wid = tid >> 6, lane = tid & 63;
  const int q = lane >> 4, rm = lane & 15;    // 16x16 emit (head)
  const int q2 = lane >> 5, n32 = lane & 31;  // 32x32 emit

  if (bid < 176) {  // ---- W1 ----
    const int dh = bid & 1;
    const int ks32 = (bid >> 1) % 11;
    const int kl = bid / 22;
    // stage: 32 l-rows x 512 d (this half), coalesced float4 reads
    for (int rr = 0; rr < 8; ++rr) {
      const int r = wid * 8 + rr;
      const int l = ks32 * 32 + r;
#pragma unroll
      for (int h = 0; h < 2; ++h) {
        const int c = h * 256 + lane * 4;
        float4 v = make_float4(0.f, 0.f, 0.f, 0.f);
        if (l < L)
          v = *(const float4*)(W1 + ((size_t)kl * L + l) * DFF + dh * 512 + c);
        uint2 p;
        p.x = pack2(v.x, v.y);
        p.y = pack2(v.z, v.w);
        *(uint2*)&sm[r][c] = p;
      }
    }
    __syncthreads();
    // emit: 16 local d-tiles x 2 k16-halves = 32 items
    for (int e = 0; e < 8; ++e) {
      const int item = wid * 8 + e;
      const int dtl = item >> 1, half = item & 1;
      const int rb = 16 * half + q2 * 8;
      const int col = dtl * 32 + n32;
      uint4 o;
      u32 w4[4];
#pragma unroll
      for (int jj = 0; jj < 4; ++jj)
        w4[jj] = (u32)sm[rb + 2 * jj][col] | ((u32)sm[rb + 2 * jj + 1][col] << 16);
      o.x = w4[0]; o.y = w4[1]; o.z = w4[2]; o.w = w4[3];
      const int dt = dh * 16 + dtl;
      const int ks = ks32 * 2 + half;
      *(uint4*)(wbuf + ((size_t)(kl * DT1 + dt) * KT1 + ks) * 512 + lane * 8) = o;
    }
  } else if (bid < 432) {  // ---- W2 ----
    const int b2i = bid - 176;
    const int ks32 = b2i & 31;
    const int kl = b2i >> 5;
    for (int rr = 0; rr < 8; ++rr) {
      const int r = wid * 8 + rr;  // local d
      const float* row = W2 + ((size_t)kl * DFF + ks32 * 32 + r) * L;
      {
        const int c = lane * 4;  // 0..255
        const float4 v = *(const float4*)(row + c);
        uint2 p;
        p.x = pack2(v.x, v.y);
        p.y = pack2(v.z, v.w);
        *(uint2*)&sm[r][c] = p;
      }
      {
        const int c = 256 + lane * 4;  // 256..511; keep c<352, zero c>=336
        if (c < 352) {
          float4 v = make_float4(0.f, 0.f, 0.f, 0.f);
          if (c < L) v = *(const float4*)(row + c);
          uint2 p;
          p.x = pack2(v.x, v.y);
          p.y = pack2(v.z, v.w);
          *(uint2*)&sm[r][c] = p;
        }
      }
    }
    __syncthreads();
    // emit: 11 l-tiles x 2 halves = 22 items
    for (int item = wid; item < 22; item += 4) {
      const int lt = item >> 1, half = item & 1;
      const int rb = 16 * half + q2 * 8;
      const int col = 32 * lt + n32;
      uint4 o;
      u32 w4[4];
#pragma unroll
      for (int jj = 0; jj < 4; ++jj)
        w4[jj] = (u32)sm[rb + 2 * jj][col] | ((u32)sm[rb + 2 * jj + 1][col] << 16);
      o.x = w4[0]; o.y = w4[1]; o.z = w4[2]; o.w = w4[3];
      const int ks = ks32 * 2 + half;
      *(uint4*)(wbuf + (size_t)NW1 * 8 +
                ((size_t)(kl * LT2 + lt) * KT2 + ks) * 512 + lane * 8) = o;
    }
  } else if (bid < 476) {  // ---- Wh (16x16 format, unchanged) ----
    const int b3i = bid - 432;
    const int ks = b3i % 11;
    const int kk = b3i / 11;
    for (int rr = 0; rr < 8; ++rr) {
      const int r = wid * 8 + rr;
      const int l = ks * 32 + r;
      if (lane < 24) {
        const int c = lane * 4;
        float4 v = make_float4(0.f, 0.f, 0.f, 0.f);
        if (l < L) v = *(const float4*)(Wh + ((size_t)kk * L + l) * O + c);
        uint2 p;
        p.x = pack2(v.x, v.y);
        p.y = pack2(v.z, v.w);
        *(uint2*)&sm[r][c] = p;
      }
    }
    __syncthreads();
    for (int nt = wid; nt < NTH; nt += 4) {
      uint4 o;
      u32 w4[4];
#pragma unroll
      for (int jj = 0; jj < 4; ++jj) {
        const u16 a = sm[q * 8 + 2 * jj][nt * 16 + rm];
        const u16 b = sm[q * 8 + 2 * jj + 1][nt * 16 + rm];
        w4[jj] = (u32)a | ((u32)b << 16);
      }
      o.x = w4[0]; o.y = w4[1]; o.z = w4[2]; o.w = w4[3];
      *(uint4*)(wbuf + (size_t)(NW1 + NW2) * 8 +
                ((size_t)(kk * NTH + nt) * KSH + ks) * 512 + lane * 8) = o;
    }
  } else {  // ---- tables ----
    __shared__ int wcnt[4][K];
    __shared__ int pre[4][K];
    __shared__ int cofs[K + 1];
    const int a = assign[tid];
    const u64 below = (1ull << lane) - 1ull;
    int myrank = 0;
#pragma unroll
    for (int k = 0; k < K; ++k) {
      const u64 m = __ballot(a == k);
      if (a == k) myrank = (int)__popcll(m & below);
      if (lane == 0) wcnt[wid][k] = (int)__popcll(m);
    }
    __syncthreads();
    if (tid == 0) {
      int tot[K];
      for (int k = 0; k < K; ++k) {
        int s = 0;
        for (int ww = 0; ww < 4; ++ww) {
          pre[ww][k] = s;
          s += wcnt[ww][k];
        }
        tot[k] = s;
      }
      cofs[0] = 0;
      for (int k = 0; k < K; ++k) cofs[k + 1] = cofs[k] + tot[k];
      for (int k = 0; k <= K; ++k) meta[512 + k] = cofs[k];
    }
    __syncthreads();
    const int pos = cofs[a] + pre[wid][a] + myrank;
    meta[256 + pos] = tid;  // chlist
    int k = 0;
    while (k < K - 1 && tid >= cofs[k + 1]) ++k;
    meta[tid] = (k << 16) | ((tid - cofs[k]) * TM);
  }
}

// ---- main kernel: 16 waves/block, 1 block/CU, 32x32x16 MFMA ----
__global__ __launch_bounds__(1024, 4) void mlp_mfma(
    const float* __restrict__ x, const float* __restrict__ rev_w,
    const float* __restrict__ rev_b, const float* __restrict__ b1,
    const float* __restrict__ b2, const float* __restrict__ bh,
    const int* __restrict__ meta, const u16* __restrict__ wbuf,
    float* __restrict__ out) {
  __shared__ __align__(16) u16 zb[TM][ZBS];  // 23.0 KB
  __shared__ __align__(16) u16 Hsh[TM][HS];  // 66.0 KB
  __shared__ float s_mean[TM], s_std[TM], s_rw[TM], s_rb[TM];
  __shared__ int s_b[TM], s_c[TM];

  const int tid = threadIdx.x;
  const int wid = tid >> 6;  // 0..15
  const int lane = tid & 63;
  const int q = lane >> 4, rm = lane & 15;    // head (16x16)
  const int q2 = lane >> 5, n32 = lane & 31;  // 32x32

  const int swz = (blockIdx.x & 7) * 32 + (blockIdx.x >> 3);
  const int info = meta[swz];
  const int kcl = info >> 16;
  const int rstart = info & 0xffff;
  const int cofs = meta[512 + kcl];
  const int cnt = meta[512 + kcl + 1] - cofs;

  // ---- RevIN: 2 rows per wave ----
  for (int i = 0; i < 2; ++i) {
    const int t = wid * 2 + i;
    const int ri = rstart + t;
    const int b = ri / cnt;
    const int c = meta[256 + cofs + (ri % cnt)];
    const float* xrow = x + (size_t)(b * C + c) * L;
    float v[6], s = 0.f, s2 = 0.f;
#pragma unroll
    for (int jj = 0; jj < 6; ++jj) {
      const int j = lane + jj * 64;
      v[jj] = (j < L) ? xrow[j] : 0.f;
      s += v[jj];
      s2 += v[jj] * v[jj];
    }
#pragma unroll
    for (int off = 32; off > 0; off >>= 1) {
      s += __shfl_down(s, off);
      s2 += __shfl_down(s2, off);
    }
    s = __shfl(s, 0);
    s2 = __shfl(s2, 0);
    const float mean = s * (1.f / L);
    const float var = s2 * (1.f / L) - mean * mean;
    const float stdv = sqrtf(var + 1e-5f);
    const float rstd = 1.f / stdv;
    const float rw = rev_w[c], rb_ = rev_b[c];
#pragma unroll
    for (int jj = 0; jj < 6; ++jj) {
      const int j = lane + jj * 64;
      if (j < L) zb[t][j] = f2bf((v[jj] - mean) * rstd * rw + rb_);
    }
    if (lane < LP - L) zb[t][L + lane] = 0;
    if (lane == 0) {
      s_mean[t] = mean;
      s_std[t] = stdv;
      s_rw[t] = rw;
      s_rb[t] = rb_;
      s_b[t] = b;
      s_c[t] = c;
    }
  }

  const u16* w1b = wbuf;
  const u16* w2b = wbuf + (size_t)NW1 * 8;
  const u16* whb = wbuf + (size_t)(NW1 + NW2) * 8;

  // preload layer-0 phase-1 ring (2 d-tiles x depth 4) before barrier
  bf16x8 a1[2][4];
  {
    const u16* b0 = w1b + (size_t)(kcl * NL) * W1FRAGS * 8 +
                    (size_t)(wid * 2) * TS1 + lane * 8;
#pragma unroll
    for (int t = 0; t < 2; ++t)
#pragma unroll
      for (int s = 0; s < 4; ++s)
        a1[t][s] = *(const bf16x8*)(b0 + (size_t)t * TS1 + s * 512);
  }
  __syncthreads();  // zb ready

  // ---- fp32 residual master (D32 layout), waves 0..10 own l-tile wid ----
  f32x16 zm;
#pragma unroll
  for (int i = 0; i < 16; ++i) zm[i] = 0.f;
  if (wid < LT2) {
#pragma unroll
    for (int g = 0; g < 4; ++g) {
      const uint2 zw = *(const uint2*)&zb[n32][32 * wid + 8 * g + 4 * q2];
      zm[4 * g + 0] = bf2f((u16)zw.x);
      zm[4 * g + 1] = bf2f((u16)(zw.x >> 16));
      zm[4 * g + 2] = bf2f((u16)zw.y);
      zm[4 * g + 3] = bf2f((u16)(zw.y >> 16));
    }
  }

  for (int l = 0; l < NL; ++l) {
    const int kl = kcl * NL + l;
    const u16* W1f = w1b + (size_t)kl * W1FRAGS * 8;
    const u16* W2f = w2b + (size_t)kl * W2FRAGS * 8;
    const float* b1p = b1 + kl * DFF;
    const float* b2p = b2 + kl * L;
    const u16* base1 = W1f + (size_t)(wid * 2) * TS1 + lane * 8;

    // -- phase 1: H = relu(z @ W1 + b1); 2 d-tiles/wave, depth-4 ring
    f32x16 acc[2];
#pragma unroll
    for (int t = 0; t < 2; ++t)
#pragma unroll
      for (int i = 0; i < 16; ++i) acc[t][i] = 0.f;
#pragma unroll
    for (int ks = 0; ks < KT1; ++ks) {
      const bf16x8 zf = *(const bf16x8*)&zb[n32][ks * 16 + q2 * 8];
#pragma unroll
      for (int t = 0; t < 2; ++t)
        acc[t] = __builtin_amdgcn_mfma_f32_32x32x16_bf16(a1[t][ks & 3], zf,
                                                         acc[t], 0, 0, 0);
      if (ks + 4 < KT1) {
#pragma unroll
        for (int t = 0; t < 2; ++t)
          a1[t][ks & 3] =
              *(const bf16x8*)(base1 + (size_t)t * TS1 + (ks + 4) * 512);
      }
    }
    // epilogue: bias+relu, write Hsh[sample][d]
#pragma unroll
    for (int t = 0; t < 2; ++t) {
      const int dt = wid * 2 + t;
#pragma unroll
      for (int g = 0; g < 4; ++g) {
        const int db = dt * 32 + 8 * g + 4 * q2;
        const float4 bq = *(const float4*)(b1p + db);
        uint2 hw;
        hw.x = pack2(fmaxf(acc[t][4 * g + 0] + bq.x, 0.f),
                     fmaxf(acc[t][4 * g + 1] + bq.y, 0.f));
        hw.y = pack2(fmaxf(acc[t][4 * g + 2] + bq.z, 0.f),
                     fmaxf(acc[t][4 * g + 3] + bq.w, 0.f));
        *(uint2*)&Hsh[n32][db] = hw;
      }
    }

    // preload phase-2 ring (depth 8) before the barrier (global-only)
    bf16x8 a2[8];
    const u16* base2 = W2f + (size_t)wid * TS2 + lane * 8;
    if (wid < LT2) {
#pragma unroll
      for (int s = 0; s < 8; ++s)
        a2[s] = *(const bf16x8*)(base2 + s * 512);
    }
    __syncthreads();  // Hsh ready

    // -- phase 2: zm += H @ W2; 1 l-tile/wave (waves 0..10), depth-8 ring
    if (wid < LT2) {
#pragma unroll
      for (int ks = 0; ks < KT2; ++ks) {
        const bf16x8 hf = *(const bf16x8*)&Hsh[n32][ks * 16 + q2 * 8];
        zm = __builtin_amdgcn_mfma_f32_32x32x16_bf16(a2[ks & 7], hf, zm, 0, 0, 0);
        if (ks + 8 < KT2)
          a2[ks & 7] = *(const bf16x8*)(base2 + (ks + 8) * 512);
      }
      // epilogue: zm += b2, refresh bf16 zb
#pragma unroll
      for (int g = 0; g < 4; ++g) {
        const int lc = 32 * wid + 8 * g + 4 * q2;
        if (lc < L) {
          const float4 bq = *(const float4*)(b2p + lc);
          zm[4 * g + 0] += bq.x;
          zm[4 * g + 1] += bq.y;
          zm[4 * g + 2] += bq.z;
          zm[4 * g + 3] += bq.w;
        }
        uint2 zw;
        zw.x = pack2(zm[4 * g + 0], zm[4 * g + 1]);
        zw.y = pack2(zm[4 * g + 2], zm[4 * g + 3]);
        *(uint2*)&zb[n32][lc] = zw;
      }
    }

    // preload next layer's phase-1 ring before the barrier (global-only)
    if (l + 1 < NL) {
      const u16* nb = w1b + (size_t)(kl + 1) * W1FRAGS * 8 +
                      (size_t)(wid * 2) * TS1 + lane * 8;
#pragma unroll
      for (int t = 0; t < 2; ++t)
#pragma unroll
        for (int s = 0; s < 4; ++s)
          a1[t][s] = *(const bf16x8*)(nb + (size_t)t * TS1 + s * 512);
    }
    __syncthreads();  // zb final for this layer
  }

  // ---- head (16x16 path): y = z @ Wh + bh, denorm, scatter out[b][o][c] ----
  if (wid < NTH) {
    const u16* Whf =
        whb + (size_t)kcl * WHFRAGS * 8 + (size_t)wid * THS + lane * 8;
    f32x4 acc0 = {0.f, 0.f, 0.f, 0.f}, acc1 = {0.f, 0.f, 0.f, 0.f};
    for (int ks = 0; ks < KSH; ++ks) {
      const bf16x8 af = *(const bf16x8*)(Whf + ks * 512);
      const bf16x8 zf0 = *(const bf16x8*)&zb[rm][ks * 32 + q * 8];
      const bf16x8 zf1 = *(const bf16x8*)&zb[rm + 16][ks * 32 + q * 8];
      acc0 = __builtin_amdgcn_mfma_f32_16x16x32_bf16(af, zf0, acc0, 0, 0, 0);
      acc1 = __builtin_amdgcn_mfma_f32_16x16x32_bf16(af, zf1, acc1, 0, 0, 0);
    }
    const float4 bq = *(const float4*)(bh + kcl * O + wid * 16 + q * 4);
    const float bqa[4] = {bq.x, bq.y, bq.z, bq.w};
#pragma unroll
    for (int rg = 0; rg < 2; ++rg) {
      const int row = rm + 16 * rg;
      const float mean = s_mean[row], stdv = s_std[row];
      const float rw = s_rw[row], rb_ = s_rb[row];
      const int ob = s_b[row], oc = s_c[row];
      const f32x4 acc = rg ? acc1 : acc0;
#pragma unroll
      for (int gg = 0; gg < 4; ++gg) {
        const int o = wid * 16 + q * 4 + gg;
        const float y = acc[gg] + bqa[gg];
        out[((size_t)ob * O + o) * C + oc] = (y - rb_) / rw * stdv + mean;
      }
    }
  }
}

extern "C" void kernel_launch(void* const* d_in, const int* in_sizes, int n_in,
                              void* d_out, int out_size, void* d_ws,
                              size_t ws_size, hipStream_t stream) {
  const float* x = (const float*)d_in[0];
  const float* rev_w = (const float*)d_in[1];
  const float* rev_b = (const float*)d_in[2];
  const float* W1 = (const float*)d_in[3];
  const float* b1 = (const float*)d_in[4];
  const float* W2 = (const float*)d_in[5];
  const float* b2 = (const float*)d_in[6];
  const float* Wh = (const float*)d_in[7];
  const float* bh = (const float*)d_in[8];
  const int* assign = (const int*)d_in[9];
  float* out = (float*)d_out;

  int* meta = (int*)d_ws;                  // ~2.1 KB
  u16* wbuf = (u16*)((char*)d_ws + 4096);  // 11.8 MB bf16 fragments

  prep<<<NPREP, 256, 0, stream>>>(assign, W1, W2, Wh, meta, wbuf);
  mlp_mfma<<<NTILES, 1024, 0, stream>>>(x, rev_w, rev_b, b1, b2, bh, meta,
                                        wbuf, out);
}